// Round 3
// baseline (265.236 us; speedup 1.0000x reference)
//
#include <hip/hip_runtime.h>
#include <hip/hip_bf16.h>

#define NFEAT 50
#define EDIM 64
#define LN_EPS 1e-5f
#define NEG_INF_C (-1000000000.0f)
#define NB 4

typedef __bf16 bf16_t;
typedef __bf16 bf16x8 __attribute__((ext_vector_type(8)));
typedef __bf16 bf16x4 __attribute__((ext_vector_type(4)));
typedef float f32x4 __attribute__((ext_vector_type(4)));

// ws layout:
//   attnT: bf16 [T][64][64], attnT[t][g][f] = attn[t][f][g], zero padded
//   WT:    bf16 [T][2][64][64], WT[t][i][e][k] = w0[t][i*64+k][e]  (B-operand ready)
//   tbT:   f32  [T][64][64], tbT[t][e][f] = tb[t][f][e], zero padded (f>=50 -> 0)
//   gwT:   f32  [64][64],    gwT[e][f]    = gw[f][e],    zero padded
//   cst:   f32  [T],         cst[t] = sum_{f,e} tb[t][f][e]*gw[f][e]

__global__ __launch_bounds__(256) void prep_kernel(
    const float* __restrict__ masker, const float* __restrict__ ln_w,
    const float* __restrict__ ln_b, const float* __restrict__ tw,
    const float* __restrict__ tb, const float* __restrict__ gw,
    bf16_t* __restrict__ ws_attnT, bf16_t* __restrict__ ws_WT,
    float* __restrict__ ws_tbT, float* __restrict__ ws_gwT,
    float* __restrict__ ws_cst)
{
  __shared__ float red[2][4];
  const int tid = threadIdx.x;
  const int lane = tid & 63;
  const int gidx = blockIdx.x * 256 + tid;   // 0..4095

  // ---- WT staging: 16384 elems, 4/thread ----
#pragma unroll
  for (int j = 0; j < 4; ++j) {
    int o = gidx * 4 + j;            // ((t*2+i)*64 + e)*64 + k
    int k = o & 63;
    int e = (o >> 6) & 63;
    int ti = o >> 12;                // t*2+i
    ws_WT[o] = (bf16_t)tw[(ti * 64 + k) * 64 + e];
  }

  // ---- tbT staging: 8192 elems, 2/thread ----
#pragma unroll
  for (int j = 0; j < 2; ++j) {
    int o = gidx * 2 + j;            // (t*64 + e)*64 + f
    int f = o & 63;
    int e = (o >> 6) & 63;
    int t = o >> 12;
    ws_tbT[o] = (f < NFEAT) ? tb[(t * NFEAT + f) * EDIM + e] : 0.f;
  }

  // ---- gwT staging: 4096 elems, 1/thread ----
  {
    int o = gidx;                    // e*64 + f
    int f = o & 63;
    int e = o >> 6;
    ws_gwT[o] = (f < NFEAT) ? gw[f * EDIM + e] : 0.f;
  }

  // ---- gate-bias constants: cst[t] = sum tb_t * gw (block 0 only) ----
  if (blockIdx.x == 0) {
    float s0 = 0.f, s1 = 0.f;
    for (int i = tid; i < NFEAT * EDIM; i += 256) {
      float g = gw[i];
      s0 += tb[i] * g;
      s1 += tb[NFEAT * EDIM + i] * g;
    }
    for (int off = 32; off > 0; off >>= 1) {
      s0 += __shfl_xor(s0, off);
      s1 += __shfl_xor(s1, off);
    }
    if (lane == 0) { red[0][tid >> 6] = s0; red[1][tid >> 6] = s1; }
    __syncthreads();
    if (tid == 0) {
      ws_cst[0] = red[0][0] + red[0][1] + red[0][2] + red[0][3];
      ws_cst[1] = red[1][0] + red[1][1] + red[1][2] + red[1][3];
    }
  }

  // ---- attention columns: 128 tasks (t,g) over 64 waves, 2 each ----
  const int wg = blockIdx.x * 4 + (tid >> 6);  // 0..63
  const int f = lane;
  const bool fv = (f < NFEAT);
  for (int i = 0; i < 2; ++i) {
    int col = wg * 2 + i;            // 0..127
    int t = col >> 6, g = col & 63;
    float val = 0.f;
    if (fv && g < NFEAT) {
      float a0 = masker[((t * 3 + 0) * NFEAT + f) * NFEAT + g];
      float a1 = masker[((t * 3 + 1) * NFEAT + f) * NFEAT + g];
      float a2 = masker[((t * 3 + 2) * NFEAT + f) * NFEAT + g];
      float prod = a0 * a1 * a2;
      val = prod > 0.f ? prod : 0.f;            // relu
    }
    float s = val;
    for (int off = 32; off > 0; off >>= 1) s += __shfl_xor(s, off);
    float mean = s / (float)NFEAT;
    float d = fv ? (val - mean) : 0.f;
    float v2 = d * d;
    for (int off = 32; off > 0; off >>= 1) v2 += __shfl_xor(v2, off);
    float var = v2 / (float)NFEAT;
    float lw = fv ? ln_w[f] : 0.f;
    float lb = fv ? ln_b[f] : 0.f;
    float aln = d * rsqrtf(var + LN_EPS) * lw + lb;
    float logit = aln + ((val != 0.f) ? 0.f : NEG_INF_C) + ((f == g) ? 1.f : 0.f);
    if (!fv) logit = -3.0e38f;
    float mx = logit;
    for (int off = 32; off > 0; off >>= 1) mx = fmaxf(mx, __shfl_xor(mx, off));
    float ex = fv ? expf(logit - mx) : 0.f;
    float se = ex;
    for (int off = 32; off > 0; off >>= 1) se += __shfl_xor(se, off);
    float attn = (fv && g < NFEAT && val != 0.f) ? (ex / se) : 0.f;
    ws_attnT[(t * 64 + g) * 64 + f] = (bf16_t)attn;
  }
}

// 512 threads = 8 waves = (4 m-tiles) x (2 t). Wave (mt,t) owns feat rows
// 16mt..16mt+15 for tensor t. Its W1/W2 B-frags (64 VGPRs) and attnT A-frags
// are loaded ONCE per block and persist -> per batch the only global loads are
// 2 feat frags (prefetched 1 batch ahead into registers freed by accP).
// t=1 waves stage H1+tb1 into sH; t=0 waves combine with gate and store.
// launch_bounds(512,4): cap 128 VGPR -> 2 blocks/CU; persistent set (~120) fits.
__global__ __launch_bounds__(512, 4) void main_kernel(
    const float* __restrict__ feat, const float* __restrict__ gb,
    const bf16_t* __restrict__ ws_attnT, const bf16_t* __restrict__ ws_WT,
    const float* __restrict__ ws_tbT, const float* __restrict__ ws_gwT,
    const float* __restrict__ ws_cst,
    float* __restrict__ out)
{
  __shared__ bf16_t sPT[2][64 * 72];   // P^T[e][g] per t, pitch 72
  __shared__ float sH[64 * 68];        // (H1+tb1)[e][f], pitch 68
  __shared__ float sLog[2][4];

  const int tid = threadIdx.x;
  const int w = tid >> 6;              // 0..7
  const int t = w >> 2;                // 0..1
  const int mt = w & 3;                // m-tile
  const int lane = tid & 63;
  const int l16 = lane & 15;
  const int lquad = lane >> 4;
  const int m0 = mt * 16;

  // ---- persistent operands (block-invariant) ----
  bf16x8 w1f[2][4], w2f[2][4];         // this t's W1/W2 B-frags: 64 VGPRs
#pragma unroll
  for (int kc = 0; kc < 2; ++kc)
#pragma unroll
    for (int n = 0; n < 4; ++n) {
      const int bo = (n * 16 + l16) * 64 + kc * 32 + lquad * 8;
      w1f[kc][n] = *(const bf16x8*)(ws_WT + (t * 2 + 0) * 4096 + bo);
      w2f[kc][n] = *(const bf16x8*)(ws_WT + (t * 2 + 1) * 4096 + bo);
    }
  bf16x8 aat[2];                       // attnT A-frags for this (t, m-tile)
#pragma unroll
  for (int kc = 0; kc < 2; ++kc)
    aat[kc] = *(const bf16x8*)(ws_attnT + (t * 64 + m0 + l16) * 64 + kc * 32 + lquad * 8);

  const float cst0 = ws_cst[0], cst1 = ws_cst[1], gbv = gb[0];
  const int fA = m0 + l16;
  const bool fAv = (fA < NFEAT);
  const int b0 = blockIdx.x * NB;
  const int foff = fA * 64 + lquad * 8;

  // ---- prefetch feat for ib = 0 ----
  f32x4 raw[4];
  if (fAv) {
    const float* fb = feat + b0 * (NFEAT * EDIM) + foff;
    raw[0] = *(const f32x4*)(fb);
    raw[1] = *(const f32x4*)(fb + 4);
    raw[2] = *(const f32x4*)(fb + 32);
    raw[3] = *(const f32x4*)(fb + 36);
  }

  for (int ib = 0; ib < NB; ++ib) {
    const int b = b0 + ib;

    // ---- convert prefetched raw -> bf16 A-frags ----
    bf16x8 a[2];
#pragma unroll
    for (int kc = 0; kc < 2; ++kc)
#pragma unroll
      for (int j = 0; j < 8; ++j) a[kc][j] = (bf16_t)0.f;
    if (fAv) {
#pragma unroll
      for (int j = 0; j < 4; ++j) {
        a[0][j] = (bf16_t)raw[0][j]; a[0][j + 4] = (bf16_t)raw[1][j];
        a[1][j] = (bf16_t)raw[2][j]; a[1][j + 4] = (bf16_t)raw[3][j];
      }
    }

    f32x4 accH[4], accP[4];
#pragma unroll
    for (int n = 0; n < 4; ++n) {
      accH[n] = (f32x4){0.f, 0.f, 0.f, 0.f};
      accP[n] = (f32x4){0.f, 0.f, 0.f, 0.f};
    }

    // ---- pass 1: all operands in registers ----
#pragma unroll
    for (int kc = 0; kc < 2; ++kc)
#pragma unroll
      for (int n = 0; n < 4; ++n) {
        accH[n] = __builtin_amdgcn_mfma_f32_16x16x32_bf16(a[kc], w1f[kc][n], accH[n], 0, 0, 0);
        accP[n] = __builtin_amdgcn_mfma_f32_16x16x32_bf16(a[kc], w2f[kc][n], accP[n], 0, 0, 0);
      }

    // ---- write P^T tile (accP dies here; its regs take next raw) ----
#pragma unroll
    for (int n = 0; n < 4; ++n) {
      bf16x4 pv;
      pv[0] = (bf16_t)accP[n][0]; pv[1] = (bf16_t)accP[n][1];
      pv[2] = (bf16_t)accP[n][2]; pv[3] = (bf16_t)accP[n][3];
      *(bf16x4*)&sPT[t][(n * 16 + l16) * 72 + m0 + lquad * 4] = pv;
    }
    __syncthreads();   // BARRIER1: sPT ready

    // ---- prefetch next batch's feat (hides under pass 2 + epilogue) ----
    if (ib + 1 < NB && fAv) {
      const float* fb = feat + (b + 1) * (NFEAT * EDIM) + foff;
      raw[0] = *(const f32x4*)(fb);
      raw[1] = *(const f32x4*)(fb + 4);
      raw[2] = *(const f32x4*)(fb + 32);
      raw[3] = *(const f32x4*)(fb + 36);
    }

    // ---- pass 2: accH += attnT_t @ P_t ----
#pragma unroll
    for (int kc = 0; kc < 2; ++kc)
#pragma unroll
      for (int n = 0; n < 4; ++n) {
        const bf16x8 bp = *(const bf16x8*)(&sPT[t][(n * 16 + l16) * 72 + kc * 32 + lquad * 8]);
        accH[n] = __builtin_amdgcn_mfma_f32_16x16x32_bf16(aat[kc], bp, accH[n], 0, 0, 0);
      }

    // ---- gate-logit partial for this (t, m-tile) ----
    float p = 0.f;
#pragma unroll
    for (int n = 0; n < 4; ++n) {
      const f32x4 gwv = *(const f32x4*)(ws_gwT + (n * 16 + l16) * 64 + m0 + lquad * 4);
#pragma unroll
      for (int r = 0; r < 4; ++r) p += accH[n][r] * gwv[r];
    }
#pragma unroll
    for (int off = 32; off > 0; off >>= 1) p += __shfl_xor(p, off);
    if (lane == 0) sLog[t][mt] = p;

    // ---- t=1 waves stage H1+tb1 into sH ----
    if (t == 1) {
#pragma unroll
      for (int n = 0; n < 4; ++n) {
        const f32x4 tbv = *(const f32x4*)(ws_tbT + 64 * 64 + (n * 16 + l16) * 64 + m0 + lquad * 4);
        f32x4 hv;
#pragma unroll
        for (int r = 0; r < 4; ++r) hv[r] = accH[n][r] + tbv[r];
        *(f32x4*)&sH[(n * 16 + l16) * 68 + m0 + lquad * 4] = hv;
      }
    }
    __syncthreads();   // BARRIER2: sLog + sH ready; also fences sPT for next iter

    // ---- gate softmax over T=2 ----
    const float g0 = sLog[0][0] + sLog[0][1] + sLog[0][2] + sLog[0][3] + cst0 + gbv;
    const float g1 = sLog[1][0] + sLog[1][1] + sLog[1][2] + sLog[1][3] + cst1 + gbv;
    const float mx = fmaxf(g0, g1);
    const float e0 = expf(g0 - mx), e1 = expf(g1 - mx);
    const float inv = 1.f / (e0 + e1);
    const float ga0 = e0 * inv, ga1 = e1 * inv;

    // ---- t=0 waves combine and store ----
    if (t == 0) {
      float* outb = out + b * (NFEAT * EDIM);
#pragma unroll
      for (int n = 0; n < 4; ++n) {
        const int ro = (n * 16 + l16) * 64 + m0 + lquad * 4;
        const f32x4 tbv = *(const f32x4*)(ws_tbT + ro);
        const f32x4 h1v = *(const f32x4*)&sH[(n * 16 + l16) * 68 + m0 + lquad * 4];
        const int e = n * 16 + l16;
#pragma unroll
        for (int r = 0; r < 4; ++r) {
          const int f = m0 + lquad * 4 + r;
          if (f < NFEAT)
            outb[f * 64 + e] = ga0 * (accH[n][r] + tbv[r]) + ga1 * h1v[r];
        }
      }
    }
  }
}

extern "C" void kernel_launch(void* const* d_in, const int* in_sizes, int n_in,
                              void* d_out, int out_size, void* d_ws, size_t ws_size,
                              hipStream_t stream) {
  const float* feat   = (const float*)d_in[0];
  const float* masker = (const float*)d_in[1];
  const float* tw     = (const float*)d_in[2];
  const float* tb     = (const float*)d_in[3];
  const float* lnw    = (const float*)d_in[4];
  const float* lnb    = (const float*)d_in[5];
  const float* gw     = (const float*)d_in[6];
  const float* gb     = (const float*)d_in[7];
  float* out = (float*)d_out;

  bf16_t* ws_attnT = (bf16_t*)d_ws;                 // 8192 bf16
  bf16_t* ws_WT    = ws_attnT + 2 * 64 * 64;        // 16384 bf16
  float*  ws_tbT   = (float*)(ws_WT + 4 * 64 * 64); // 8192 f32
  float*  ws_gwT   = ws_tbT + 2 * 64 * 64;          // 4096 f32
  float*  ws_cst   = ws_gwT + 64 * 64;              // 2 f32

  prep_kernel<<<16, 256, 0, stream>>>(masker, lnw, lnb, tw, tb, gw,
                                      ws_attnT, ws_WT, ws_tbT, ws_gwT, ws_cst);
  main_kernel<<<4096 / NB, 512, 0, stream>>>(feat, gb, ws_attnT, ws_WT,
                                             ws_tbT, ws_gwT, ws_cst, out);
}

// Round 4
// 138.127 us; speedup vs baseline: 1.9202x; 1.9202x over previous
//
#include <hip/hip_runtime.h>
#include <hip/hip_bf16.h>

#define NFEAT 50
#define EDIM 64
#define LN_EPS 1e-5f
#define NEG_INF_C (-1000000000.0f)
#define NB 4

typedef __bf16 bf16_t;
typedef __bf16 bf16x8 __attribute__((ext_vector_type(8)));
typedef __bf16 bf16x4 __attribute__((ext_vector_type(4)));
typedef float f32x4 __attribute__((ext_vector_type(4)));

// ws layout:
//   attnT: bf16 [T][64][64], attnT[t][g][f] = attn[t][f][g], zero padded
//   WT:    bf16 [T][2][64][64] XOR-SWIZZLED: slot (ti,e,c,j) holds
//          w0[t][ (c^(e&7))*8+j , e ] -- so main can copy it linearly into LDS
//          and read chunk ((kc*4+lquad)^(e&7)) conflict-free (2-way max).
//   tbT:   f32  [T][64][64], tbT[t][e][f] = tb[t][f][e], zero padded (f>=50 -> 0)
//   gwT:   f32  [64][64],    gwT[e][f]    = gw[f][e],    zero padded
//   cst:   f32  [T],         cst[t] = sum_{f,e} tb[t][f][e]*gw[f][e]

__global__ __launch_bounds__(256) void prep_kernel(
    const float* __restrict__ masker, const float* __restrict__ ln_w,
    const float* __restrict__ ln_b, const float* __restrict__ tw,
    const float* __restrict__ tb, const float* __restrict__ gw,
    bf16_t* __restrict__ ws_attnT, bf16_t* __restrict__ ws_WT,
    float* __restrict__ ws_tbT, float* __restrict__ ws_gwT,
    float* __restrict__ ws_cst)
{
  __shared__ float red[2][4];
  const int tid = threadIdx.x;
  const int lane = tid & 63;
  const int gidx = blockIdx.x * 256 + tid;   // 0..4095

  // ---- WT staging (swizzled): 16384 elems, 4/thread ----
#pragma unroll
  for (int j = 0; j < 4; ++j) {
    int o = gidx * 4 + j;            // output slot: ((ti*64 + e)*64 + kl)
    int kl = o & 63;                 // slot within row
    int e = (o >> 6) & 63;
    int ti = o >> 12;                // t*2+i
    int k = ((kl >> 3) ^ (e & 7)) * 8 + (kl & 7);   // logical k for this slot
    ws_WT[o] = (bf16_t)tw[(ti * 64 + k) * 64 + e];
  }

  // ---- tbT staging: 8192 elems, 2/thread ----
#pragma unroll
  for (int j = 0; j < 2; ++j) {
    int o = gidx * 2 + j;            // (t*64 + e)*64 + f
    int f = o & 63;
    int e = (o >> 6) & 63;
    int t = o >> 12;
    ws_tbT[o] = (f < NFEAT) ? tb[(t * NFEAT + f) * EDIM + e] : 0.f;
  }

  // ---- gwT staging: 4096 elems, 1/thread ----
  {
    int o = gidx;                    // e*64 + f
    int f = o & 63;
    int e = o >> 6;
    ws_gwT[o] = (f < NFEAT) ? gw[f * EDIM + e] : 0.f;
  }

  // ---- gate-bias constants: cst[t] = sum tb_t * gw (block 0 only) ----
  if (blockIdx.x == 0) {
    float s0 = 0.f, s1 = 0.f;
    for (int i = tid; i < NFEAT * EDIM; i += 256) {
      float g = gw[i];
      s0 += tb[i] * g;
      s1 += tb[NFEAT * EDIM + i] * g;
    }
    for (int off = 32; off > 0; off >>= 1) {
      s0 += __shfl_xor(s0, off);
      s1 += __shfl_xor(s1, off);
    }
    if (lane == 0) { red[0][tid >> 6] = s0; red[1][tid >> 6] = s1; }
    __syncthreads();
    if (tid == 0) {
      ws_cst[0] = red[0][0] + red[0][1] + red[0][2] + red[0][3];
      ws_cst[1] = red[1][0] + red[1][1] + red[1][2] + red[1][3];
    }
  }

  // ---- attention columns: 128 tasks (t,g) over 64 waves, 2 each ----
  const int wg = blockIdx.x * 4 + (tid >> 6);  // 0..63
  const int f = lane;
  const bool fv = (f < NFEAT);
  for (int i = 0; i < 2; ++i) {
    int col = wg * 2 + i;            // 0..127
    int t = col >> 6, g = col & 63;
    float val = 0.f;
    if (fv && g < NFEAT) {
      float a0 = masker[((t * 3 + 0) * NFEAT + f) * NFEAT + g];
      float a1 = masker[((t * 3 + 1) * NFEAT + f) * NFEAT + g];
      float a2 = masker[((t * 3 + 2) * NFEAT + f) * NFEAT + g];
      float prod = a0 * a1 * a2;
      val = prod > 0.f ? prod : 0.f;            // relu
    }
    float s = val;
    for (int off = 32; off > 0; off >>= 1) s += __shfl_xor(s, off);
    float mean = s / (float)NFEAT;
    float d = fv ? (val - mean) : 0.f;
    float v2 = d * d;
    for (int off = 32; off > 0; off >>= 1) v2 += __shfl_xor(v2, off);
    float var = v2 / (float)NFEAT;
    float lw = fv ? ln_w[f] : 0.f;
    float lb = fv ? ln_b[f] : 0.f;
    float aln = d * rsqrtf(var + LN_EPS) * lw + lb;
    float logit = aln + ((val != 0.f) ? 0.f : NEG_INF_C) + ((f == g) ? 1.f : 0.f);
    if (!fv) logit = -3.0e38f;
    float mx = logit;
    for (int off = 32; off > 0; off >>= 1) mx = fmaxf(mx, __shfl_xor(mx, off));
    float ex = fv ? expf(logit - mx) : 0.f;
    float se = ex;
    for (int off = 32; off > 0; off >>= 1) se += __shfl_xor(se, off);
    float attn = (fv && g < NFEAT && val != 0.f) ? (ex / se) : 0.f;
    ws_attnT[(t * 64 + g) * 64 + f] = (bf16_t)attn;
  }
}

// R0 structure (the only non-spilling one): 256 threads, 4 waves, merged t,
// NB=4 batches/block, NO launch_bounds VGPR cap (R1/R3 lesson: caps -> spill).
// New: WT (batch-invariant, 32KB) staged ONCE per block into LDS (swizzled),
// so per-batch pass-1 B-frags are ds_read_b128 (conflict-free) instead of 32
// global L2 loads that every __syncthreads re-drains.
__global__ __launch_bounds__(256) void main_kernel(
    const float* __restrict__ feat, const float* __restrict__ gb,
    const bf16_t* __restrict__ ws_attnT, const bf16_t* __restrict__ ws_WT,
    const float* __restrict__ ws_tbT, const float* __restrict__ ws_gwT,
    const float* __restrict__ ws_cst,
    float* __restrict__ out)
{
  __shared__ bf16_t sWT[4 * 64 * 64];  // 32 KB, swizzled [ti][e][chunk^e&7][8]
  __shared__ bf16_t sPT[2][64 * 72];   // P^T[e][f'] per t, pitch 72
  __shared__ float sLog[2][4];

  const int tid = threadIdx.x;
  const int w = tid >> 6;
  const int lane = tid & 63;
  const int l16 = lane & 15;
  const int lquad = lane >> 4;
  const int m0 = w * 16;

  // ---- stage WT into LDS (linear copy; global is pre-swizzled) ----
#pragma unroll
  for (int it = 0; it < 8; ++it) {
    const int idx = it * 256 + tid;    // 16B chunk id, 0..2047
    *(bf16x8*)&sWT[idx * 8] = *(const bf16x8*)(ws_WT + idx * 8);
  }

  // ---- block-invariant register state ----
  bf16x8 aat[2][2];                    // attnT A-frags (rows g = m0+l16)
#pragma unroll
  for (int t = 0; t < 2; ++t)
#pragma unroll
    for (int kc = 0; kc < 2; ++kc)
      aat[t][kc] = *(const bf16x8*)(ws_attnT + (t * 64 + m0 + l16) * 64 + kc * 32 + lquad * 8);

  const float cst0 = ws_cst[0], cst1 = ws_cst[1], gbv = gb[0];
  const int fA = m0 + l16;
  const bool fAv = (fA < NFEAT);
  const int b0 = blockIdx.x * NB;
  const int foff = fA * 64 + lquad * 8;
  const int exl = l16 & 7;             // e&7 for this lane (same for all n)

  // ---- prefetch feat for ib = 0 ----
  f32x4 raw[4];
  if (fAv) {
    const float* fb = feat + b0 * (NFEAT * EDIM) + foff;
    raw[0] = *(const f32x4*)(fb);
    raw[1] = *(const f32x4*)(fb + 4);
    raw[2] = *(const f32x4*)(fb + 32);
    raw[3] = *(const f32x4*)(fb + 36);
  }

  __syncthreads();                     // sWT ready

#pragma unroll 1
  for (int ib = 0; ib < NB; ++ib) {
    const int b = b0 + ib;

    // ---- convert prefetched raw -> bf16 A-frags ----
    bf16x8 a[2];
#pragma unroll
    for (int kc = 0; kc < 2; ++kc)
#pragma unroll
      for (int j = 0; j < 8; ++j) a[kc][j] = (bf16_t)0.f;
    if (fAv) {
#pragma unroll
      for (int j = 0; j < 4; ++j) {
        a[0][j] = (bf16_t)raw[0][j]; a[0][j + 4] = (bf16_t)raw[1][j];
        a[1][j] = (bf16_t)raw[2][j]; a[1][j + 4] = (bf16_t)raw[3][j];
      }
    }

    // ---- issue prefetch for next batch (overlaps pass1) ----
    if (ib + 1 < NB && fAv) {
      const float* fb = feat + (b + 1) * (NFEAT * EDIM) + foff;
      raw[0] = *(const f32x4*)(fb);
      raw[1] = *(const f32x4*)(fb + 4);
      raw[2] = *(const f32x4*)(fb + 32);
      raw[3] = *(const f32x4*)(fb + 36);
    }

    f32x4 accH[2][4], accP[2][4];
#pragma unroll
    for (int t = 0; t < 2; ++t)
#pragma unroll
      for (int n = 0; n < 4; ++n) {
        accH[t][n] = (f32x4){0.f, 0.f, 0.f, 0.f};
        accP[t][n] = (f32x4){0.f, 0.f, 0.f, 0.f};
      }

    // ---- pass 1: B-frags from LDS (swizzled chunk), 4 indep MFMA streams ----
#pragma unroll
    for (int kc = 0; kc < 2; ++kc) {
      const int chunk = ((kc * 4 + lquad) ^ exl) * 8;
#pragma unroll
      for (int n = 0; n < 4; ++n) {
        const int ro = (n * 16 + l16) * 64 + chunk;
        const bf16x8 b10 = *(const bf16x8*)(&sWT[0 * 4096 + ro]);  // t0 W1
        const bf16x8 b20 = *(const bf16x8*)(&sWT[1 * 4096 + ro]);  // t0 W2
        const bf16x8 b11 = *(const bf16x8*)(&sWT[2 * 4096 + ro]);  // t1 W1
        const bf16x8 b21 = *(const bf16x8*)(&sWT[3 * 4096 + ro]);  // t1 W2
        accH[0][n] = __builtin_amdgcn_mfma_f32_16x16x32_bf16(a[kc], b10, accH[0][n], 0, 0, 0);
        accP[0][n] = __builtin_amdgcn_mfma_f32_16x16x32_bf16(a[kc], b20, accP[0][n], 0, 0, 0);
        accH[1][n] = __builtin_amdgcn_mfma_f32_16x16x32_bf16(a[kc], b11, accH[1][n], 0, 0, 0);
        accP[1][n] = __builtin_amdgcn_mfma_f32_16x16x32_bf16(a[kc], b21, accP[1][n], 0, 0, 0);
      }
    }

    // ---- write both P^T tiles to LDS ----
#pragma unroll
    for (int t = 0; t < 2; ++t)
#pragma unroll
      for (int n = 0; n < 4; ++n) {
        bf16x4 pv;
        pv[0] = (bf16_t)accP[t][n][0]; pv[1] = (bf16_t)accP[t][n][1];
        pv[2] = (bf16_t)accP[t][n][2]; pv[3] = (bf16_t)accP[t][n][3];
        *(bf16x4*)&sPT[t][(n * 16 + l16) * 72 + m0 + lquad * 4] = pv;
      }
    __syncthreads();   // BARRIER1: sPT ready

    // ---- pass 2: accH[t] += attnT_t @ P_t ----
#pragma unroll
    for (int kc = 0; kc < 2; ++kc) {
#pragma unroll
      for (int n = 0; n < 4; ++n) {
        const int so = (n * 16 + l16) * 72 + kc * 32 + lquad * 8;
        const bf16x8 bp0 = *(const bf16x8*)(&sPT[0][so]);
        const bf16x8 bp1 = *(const bf16x8*)(&sPT[1][so]);
        accH[0][n] = __builtin_amdgcn_mfma_f32_16x16x32_bf16(aat[0][kc], bp0, accH[0][n], 0, 0, 0);
        accH[1][n] = __builtin_amdgcn_mfma_f32_16x16x32_bf16(aat[1][kc], bp1, accH[1][n], 0, 0, 0);
      }
    }

    // ---- gate-logit partials: p_t = sum accH_t * gw (tb folded into cst) ----
    float p0 = 0.f, p1 = 0.f;
#pragma unroll
    for (int n = 0; n < 4; ++n) {
      const f32x4 gwv = *(const f32x4*)(ws_gwT + (n * 16 + l16) * 64 + m0 + lquad * 4);
#pragma unroll
      for (int r = 0; r < 4; ++r) {
        p0 += accH[0][n][r] * gwv[r];
        p1 += accH[1][n][r] * gwv[r];
      }
    }
#pragma unroll
    for (int off = 32; off > 0; off >>= 1) {
      p0 += __shfl_xor(p0, off);
      p1 += __shfl_xor(p1, off);
    }
    if (lane == 0) { sLog[0][w] = p0; sLog[1][w] = p1; }
    __syncthreads();   // BARRIER2: sLog visible; fences sPT for next iter

    // ---- gate softmax over T=2, weighted sum (+tb at store), store ----
    const float g0 = sLog[0][0] + sLog[0][1] + sLog[0][2] + sLog[0][3] + cst0 + gbv;
    const float g1 = sLog[1][0] + sLog[1][1] + sLog[1][2] + sLog[1][3] + cst1 + gbv;
    const float mx = fmaxf(g0, g1);
    const float e0 = expf(g0 - mx), e1 = expf(g1 - mx);
    const float inv = 1.f / (e0 + e1);
    const float ga0 = e0 * inv, ga1 = e1 * inv;

    float* outb = out + b * (NFEAT * EDIM);
#pragma unroll
    for (int n = 0; n < 4; ++n) {
      const int ro = (n * 16 + l16) * 64 + m0 + lquad * 4;
      const f32x4 tbv0 = *(const f32x4*)(ws_tbT + ro);
      const f32x4 tbv1 = *(const f32x4*)(ws_tbT + 64 * 64 + ro);
      const int e = n * 16 + l16;
#pragma unroll
      for (int r = 0; r < 4; ++r) {
        const int f = m0 + lquad * 4 + r;
        if (f < NFEAT)
          outb[f * 64 + e] = ga0 * (accH[0][n][r] + tbv0[r])
                           + ga1 * (accH[1][n][r] + tbv1[r]);
      }
    }
  }
}

extern "C" void kernel_launch(void* const* d_in, const int* in_sizes, int n_in,
                              void* d_out, int out_size, void* d_ws, size_t ws_size,
                              hipStream_t stream) {
  const float* feat   = (const float*)d_in[0];
  const float* masker = (const float*)d_in[1];
  const float* tw     = (const float*)d_in[2];
  const float* tb     = (const float*)d_in[3];
  const float* lnw    = (const float*)d_in[4];
  const float* lnb    = (const float*)d_in[5];
  const float* gw     = (const float*)d_in[6];
  const float* gb     = (const float*)d_in[7];
  float* out = (float*)d_out;

  bf16_t* ws_attnT = (bf16_t*)d_ws;                 // 8192 bf16
  bf16_t* ws_WT    = ws_attnT + 2 * 64 * 64;        // 16384 bf16
  float*  ws_tbT   = (float*)(ws_WT + 4 * 64 * 64); // 8192 f32
  float*  ws_gwT   = ws_tbT + 2 * 64 * 64;          // 4096 f32
  float*  ws_cst   = ws_gwT + 64 * 64;              // 2 f32

  prep_kernel<<<16, 256, 0, stream>>>(masker, lnw, lnb, tw, tb, gw,
                                      ws_attnT, ws_WT, ws_tbT, ws_gwT, ws_cst);
  main_kernel<<<4096 / NB, 256, 0, stream>>>(feat, gb, ws_attnT, ws_WT,
                                             ws_tbT, ws_gwT, ws_cst, out);
}